// Round 1
// baseline (561.353 us; speedup 1.0000x reference)
//
#include <hip/hip_runtime.h>
#include <stdint.h>

// Problem dims (fixed by the reference): out[M,N] = x[M,K] @ w_eff[N,K]^T + bias[N]
#define M_DIM 8192
#define N_DIM 4096
#define K_DIM 4096

#define BM 128
#define BN 128
#define BK 32

typedef float v4f __attribute__((ext_vector_type(4)));
typedef __bf16 v8bf __attribute__((ext_vector_type(8)));

typedef __attribute__((address_space(3))) uint32_t lds_u32_t;
typedef const __attribute__((address_space(1))) uint32_t glb_u32_t;

__device__ inline uint16_t f2bf(float f) {
    union { float f; uint32_t u; } v; v.f = f;
    uint32_t r = v.u + 0x7fffu + ((v.u >> 16) & 1u);   // round-to-nearest-even
    return (uint16_t)(r >> 16);
}

// ---------------- kernel 1: x fp32 -> bf16 ----------------
__global__ __launch_bounds__(256) void cvt_x(const float* __restrict__ x,
                                             uint16_t* __restrict__ xb,
                                             long long n8) {
    long long i = (long long)blockIdx.x * 256 + threadIdx.x;
    if (i >= n8) return;
    const float4* x4 = (const float4*)x;
    float4 a = x4[2 * i];
    float4 b = x4[2 * i + 1];
    union { uint16_t h[8]; uint4 u; } o;
    o.h[0] = f2bf(a.x); o.h[1] = f2bf(a.y); o.h[2] = f2bf(a.z); o.h[3] = f2bf(a.w);
    o.h[4] = f2bf(b.x); o.h[5] = f2bf(b.y); o.h[6] = f2bf(b.z); o.h[7] = f2bf(b.w);
    ((uint4*)xb)[i] = o.u;
}

// ---------------- kernel 2: build w_eff (bf16, [N,K] = B^T layout) ----------------
// Per row: mu = mean(w), scale = mean(|w-mu|) (both fp64 to avoid sign-flip
// mismatches vs the numpy reference near w==mu). Then per flat 8-window keep
// the |w|-argmax element at full precision, others = sign(w-mu)*scale.
__global__ __launch_bounds__(256) void make_weff(const float* __restrict__ w,
                                                 uint16_t* __restrict__ weff) {
    __shared__ double red[4];
    int row  = blockIdx.x;
    int tid  = threadIdx.x;
    int lane = tid & 63;
    int wid  = tid >> 6;

    const float* wr = w + (size_t)row * K_DIM;
    const float4* w4 = (const float4*)wr + tid * 4;   // 16 contiguous elems / thread
    float4 r0 = w4[0], r1 = w4[1], r2 = w4[2], r3 = w4[3];
    float v[16] = { r0.x, r0.y, r0.z, r0.w, r1.x, r1.y, r1.z, r1.w,
                    r2.x, r2.y, r2.z, r2.w, r3.x, r3.y, r3.z, r3.w };

    double s = 0.0;
#pragma unroll
    for (int j = 0; j < 16; j++) s += (double)v[j];
#pragma unroll
    for (int off = 32; off > 0; off >>= 1) s += __shfl_down(s, off);
    if (lane == 0) red[wid] = s;
    __syncthreads();
    double mu = (red[0] + red[1] + red[2] + red[3]) * (1.0 / 4096.0);
    __syncthreads();

    double sa = 0.0;
#pragma unroll
    for (int j = 0; j < 16; j++) sa += fabs((double)v[j] - mu);
#pragma unroll
    for (int off = 32; off > 0; off >>= 1) sa += __shfl_down(sa, off);
    if (lane == 0) red[wid] = sa;
    __syncthreads();
    double scale = (red[0] + red[1] + red[2] + red[3]) * (1.0 / 4096.0);

    float scf = (float)scale;
    union { uint16_t h[16]; uint4 u[2]; } o;
#pragma unroll
    for (int w2 = 0; w2 < 2; w2++) {
        int base = w2 * 8;
        int amax = 0;
        float mx = fabsf(v[base]);
#pragma unroll
        for (int j = 1; j < 8; j++) {
            float aj = fabsf(v[base + j]);
            if (aj > mx) { mx = aj; amax = j; }   // strict > keeps first occurrence (jnp.argmax)
        }
#pragma unroll
        for (int j = 0; j < 8; j++) {
            double wc = (double)v[base + j] - mu;
            float q = (wc > 0.0) ? scf : ((wc < 0.0) ? -scf : 0.0f);
            o.h[base + j] = f2bf((j == amax) ? v[base + j] : q);
        }
    }
    uint4* dst = (uint4*)(weff + (size_t)row * K_DIM + (size_t)tid * 16);
    dst[0] = o.u[0];
    dst[1] = o.u[1];
}

// ---------------- kernel 3: bf16 MFMA GEMM (m97 structure) ----------------
// A [M,K] bf16 row-major, B [N,K] bf16 row-major (i.e. B^T input), C fp32 [M,N].
__device__ inline void async_cp16(const uint16_t* g, uint16_t* lds_uniform) {
    __builtin_amdgcn_global_load_lds((glb_u32_t*)g, (lds_u32_t*)lds_uniform, 16, 0, 0);
}

__global__ __launch_bounds__(256, 2) void gemm_bt(const uint16_t* __restrict__ A,
                                                  const uint16_t* __restrict__ B,
                                                  const float* __restrict__ bias,
                                                  float* __restrict__ C) {
    __shared__ __attribute__((aligned(16))) uint16_t As[BM * BK];   // 8 KB, unpadded (global_load_lds layout)
    __shared__ __attribute__((aligned(16))) uint16_t Bs[BN * BK];   // 8 KB

    int tid  = threadIdx.x;
    int lane = tid & 63;
    int wid  = tid >> 6;          // 4 waves
    int wm   = wid >> 1;          // wave row (0..1) -> 64 rows of the 128-tile
    int wn   = wid & 1;           // wave col (0..1) -> 64 cols

    long long bm = (long long)blockIdx.y * BM;
    long long bn = (long long)blockIdx.x * BN;

    v4f acc[4][4];
#pragma unroll
    for (int i = 0; i < 4; i++)
#pragma unroll
        for (int j = 0; j < 4; j++) acc[i][j] = (v4f)(0.0f);

    const uint16_t* Ab = A + (size_t)bm * K_DIM;
    const uint16_t* Bb = B + (size_t)bn * K_DIM;

    // Staging: 512 chunks of 16B per 128x32 tile. chunk c -> row=c>>2, col8=(c&3)*8,
    // LDS byte off = c*16 (matches HW's wave-uniform-base + lane*16 write pattern).
    int c0 = wid * 64 + lane;          // it 0
    int c1 = c0 + 256;                 // it 1
    int ar0 = c0 >> 2, ac0 = (c0 & 3) * 8;
    int ar1 = c1 >> 2, ac1 = (c1 & 3) * 8;
    uint16_t* a_dst0 = As + wid * 512;           // bytes: wid*64*16
    uint16_t* a_dst1 = As + 2048 + wid * 512;
    uint16_t* b_dst0 = Bs + wid * 512;
    uint16_t* b_dst1 = Bs + 2048 + wid * 512;

    int frow = lane & 15;
    int quad = lane >> 4;

    for (int k0 = 0; k0 < K_DIM; k0 += BK) {
        async_cp16(Ab + (size_t)ar0 * K_DIM + k0 + ac0, a_dst0);
        async_cp16(Ab + (size_t)ar1 * K_DIM + k0 + ac1, a_dst1);
        async_cp16(Bb + (size_t)ar0 * K_DIM + k0 + ac0, b_dst0);
        async_cp16(Bb + (size_t)ar1 * K_DIM + k0 + ac1, b_dst1);
        __syncthreads();   // compiler emits vmcnt(0) drain before s_barrier

        v8bf af[4], bfr[4];
#pragma unroll
        for (int i = 0; i < 4; i++)
            af[i] = *(const v8bf*)&As[(wm * 64 + i * 16 + frow) * BK + quad * 8];
#pragma unroll
        for (int j = 0; j < 4; j++)
            bfr[j] = *(const v8bf*)&Bs[(wn * 64 + j * 16 + frow) * BK + quad * 8];

#pragma unroll
        for (int i = 0; i < 4; i++)
#pragma unroll
            for (int j = 0; j < 4; j++)
                acc[i][j] = __builtin_amdgcn_mfma_f32_16x16x32_bf16(af[i], bfr[j], acc[i][j], 0, 0, 0);
        __syncthreads();
    }

    // Epilogue: C/D layout col = lane&15, row = quad*4 + reg. Fuse bias.
    int n0 = (int)bn + wn * 64 + frow;
    int m0 = (int)bm + wm * 64 + quad * 4;
#pragma unroll
    for (int j = 0; j < 4; j++) {
        float bj = bias[n0 + j * 16];
#pragma unroll
        for (int i = 0; i < 4; i++) {
            size_t base = (size_t)(m0 + i * 16) * N_DIM + (size_t)(n0 + j * 16);
#pragma unroll
            for (int r = 0; r < 4; r++)
                C[base + (size_t)r * N_DIM] = acc[i][j][r] + bj;
        }
    }
}

extern "C" void kernel_launch(void* const* d_in, const int* in_sizes, int n_in,
                              void* d_out, int out_size, void* d_ws, size_t ws_size,
                              hipStream_t stream) {
    const float* x    = (const float*)d_in[0];   // [4,2048,4096]
    const float* w    = (const float*)d_in[1];   // [4096,4096]
    const float* bias = (const float*)d_in[2];   // [4096]
    float* out = (float*)d_out;

    uint16_t* xb   = (uint16_t*)d_ws;                                        // 67,108,864 B
    uint16_t* weff = (uint16_t*)((char*)d_ws + (size_t)M_DIM * K_DIM * 2);   // +33,554,432 B

    long long n8 = (long long)M_DIM * K_DIM / 8;
    cvt_x<<<dim3((unsigned)((n8 + 255) / 256)), dim3(256), 0, stream>>>(x, xb, n8);
    make_weff<<<dim3(N_DIM), dim3(256), 0, stream>>>(w, weff);
    gemm_bt<<<dim3(N_DIM / BN, M_DIM / BM), dim3(256), 0, stream>>>(xb, weff, bias, out);
}

// Round 2
// 529.354 us; speedup vs baseline: 1.0604x; 1.0604x over previous
//
#include <hip/hip_runtime.h>
#include <stdint.h>

// out[M,N] = x[M,K] @ w_eff[N,K]^T + bias[N]
#define M_DIM 8192
#define N_DIM 4096
#define K_DIM 4096

#define BM 128
#define BN 128
#define BK 64

typedef float v16f __attribute__((ext_vector_type(16)));
typedef __bf16 v8bf __attribute__((ext_vector_type(8)));

typedef __attribute__((address_space(3))) uint32_t lds_u32_t;
typedef const __attribute__((address_space(1))) uint32_t glb_u32_t;

__device__ inline uint16_t f2bf(float f) {
    union { float f; uint32_t u; } v; v.f = f;
    uint32_t r = v.u + 0x7fffu + ((v.u >> 16) & 1u);   // RNE
    return (uint16_t)(r >> 16);
}

// ---------------- kernel 1: x fp32 -> bf16 ----------------
__global__ __launch_bounds__(256) void cvt_x(const float* __restrict__ x,
                                             uint16_t* __restrict__ xb,
                                             long long n8) {
    long long i = (long long)blockIdx.x * 256 + threadIdx.x;
    if (i >= n8) return;
    const float4* x4 = (const float4*)x;
    float4 a = x4[2 * i];
    float4 b = x4[2 * i + 1];
    union { uint16_t h[8]; uint4 u; } o;
    o.h[0] = f2bf(a.x); o.h[1] = f2bf(a.y); o.h[2] = f2bf(a.z); o.h[3] = f2bf(a.w);
    o.h[4] = f2bf(b.x); o.h[5] = f2bf(b.y); o.h[6] = f2bf(b.z); o.h[7] = f2bf(b.w);
    ((uint4*)xb)[i] = o.u;
}

// ---------------- kernel 2: build w_eff (bf16, [N,K] = B^T layout) ----------------
__global__ __launch_bounds__(256) void make_weff(const float* __restrict__ w,
                                                 uint16_t* __restrict__ weff) {
    __shared__ double red[4];
    int row  = blockIdx.x;
    int tid  = threadIdx.x;
    int lane = tid & 63;
    int wid  = tid >> 6;

    const float* wr = w + (size_t)row * K_DIM;
    const float4* w4 = (const float4*)wr + tid * 4;
    float4 r0 = w4[0], r1 = w4[1], r2 = w4[2], r3 = w4[3];
    float v[16] = { r0.x, r0.y, r0.z, r0.w, r1.x, r1.y, r1.z, r1.w,
                    r2.x, r2.y, r2.z, r2.w, r3.x, r3.y, r3.z, r3.w };

    double s = 0.0;
#pragma unroll
    for (int j = 0; j < 16; j++) s += (double)v[j];
#pragma unroll
    for (int off = 32; off > 0; off >>= 1) s += __shfl_down(s, off);
    if (lane == 0) red[wid] = s;
    __syncthreads();
    double mu = (red[0] + red[1] + red[2] + red[3]) * (1.0 / 4096.0);
    __syncthreads();

    double sa = 0.0;
#pragma unroll
    for (int j = 0; j < 16; j++) sa += fabs((double)v[j] - mu);
#pragma unroll
    for (int off = 32; off > 0; off >>= 1) sa += __shfl_down(sa, off);
    if (lane == 0) red[wid] = sa;
    __syncthreads();
    double scale = (red[0] + red[1] + red[2] + red[3]) * (1.0 / 4096.0);

    float scf = (float)scale;
    union { uint16_t h[16]; uint4 u[2]; } o;
#pragma unroll
    for (int w2 = 0; w2 < 2; w2++) {
        int base = w2 * 8;
        int amax = 0;
        float mx = fabsf(v[base]);
#pragma unroll
        for (int j = 1; j < 8; j++) {
            float aj = fabsf(v[base + j]);
            if (aj > mx) { mx = aj; amax = j; }
        }
#pragma unroll
        for (int j = 0; j < 8; j++) {
            double wc = (double)v[base + j] - mu;
            float q = (wc > 0.0) ? scf : ((wc < 0.0) ? -scf : 0.0f);
            o.h[base + j] = f2bf((j == amax) ? v[base + j] : q);
        }
    }
    uint4* dst = (uint4*)(weff + (size_t)row * K_DIM + (size_t)tid * 16);
    dst[0] = o.u[0];
    dst[1] = o.u[1];
}

// ---------------- kernel 3: bf16 MFMA GEMM, 32x32x16, BK=64, XOR-swizzled LDS ----------------
// LDS layout: tile rows of 8 chunks (16 B each); chunk (r,c) stored at slot c^(r&7).
// Swizzle is baked into the GLOBAL fetch address because global_load_lds writes
// lane i at uniform_base + i*16 (wave-uniform dst, no per-lane scatter).
__device__ inline void async_cp16(const uint16_t* g, uint16_t* lds_uniform) {
    __builtin_amdgcn_global_load_lds((glb_u32_t*)g, (lds_u32_t*)lds_uniform, 16, 0, 0);
}

__global__ __launch_bounds__(256, 4) void gemm_bt(const uint16_t* __restrict__ A,
                                                  const uint16_t* __restrict__ B,
                                                  const float* __restrict__ bias,
                                                  float* __restrict__ C) {
    __shared__ __attribute__((aligned(16))) uint16_t As[BM * BK];   // 16 KB
    __shared__ __attribute__((aligned(16))) uint16_t Bs[BN * BK];   // 16 KB

    int tid  = threadIdx.x;
    int lane = tid & 63;
    int wid  = tid >> 6;          // 4 waves, 2x2 over the 128x128 tile
    int wm   = wid >> 1;
    int wn   = wid & 1;
    int half = lane >> 5;         // 32-lane half of the wave
    int ml   = lane & 31;

    long long bm = (long long)blockIdx.y * BM;
    long long bn = (long long)blockIdx.x * BN;

    v16f acc[2][2];
#pragma unroll
    for (int t = 0; t < 2; t++)
#pragma unroll
        for (int u = 0; u < 2; u++) acc[t][u] = (v16f)(0.0f);

    const uint16_t* Ab = A + (size_t)bm * K_DIM;
    const uint16_t* Bb = B + (size_t)bn * K_DIM;

    // Staging: 1024 chunks (16B) per 128x64 tile; instruction ib covers chunks
    // [ib*64, ib*64+64). Lane's chunk: row = ib*8 + (lane>>3), stored col = lane&7,
    // global col = (lane&7) ^ (row&7)  [row&7 == lane>>3 since ib*8 is 8-aligned].
    int lrow = lane >> 3;
    int cg   = (lane & 7) ^ lrow;

    for (int k0 = 0; k0 < K_DIM; k0 += BK) {
#pragma unroll
        for (int q = 0; q < 4; q++) {
            int ib = wid * 4 + q;
            int r  = ib * 8 + lrow;
            const size_t go = (size_t)r * K_DIM + k0 + cg * 8;
            async_cp16(Ab + go, As + ib * 512);
            async_cp16(Bb + go, Bs + ib * 512);
        }
        __syncthreads();

#pragma unroll
        for (int s = 0; s < 4; s++) {         // 4 k-steps of 16
            int cc = s * 2 + half;            // logical chunk col for this lane
            v8bf af[2], bfv[2];
#pragma unroll
            for (int t = 0; t < 2; t++) {
                int r = wm * 64 + t * 32 + ml;
                af[t] = *(const v8bf*)&As[r * BK + ((cc ^ (r & 7)) * 8)];
            }
#pragma unroll
            for (int u = 0; u < 2; u++) {
                int r = wn * 64 + u * 32 + ml;
                bfv[u] = *(const v8bf*)&Bs[r * BK + ((cc ^ (r & 7)) * 8)];
            }
#pragma unroll
            for (int t = 0; t < 2; t++)
#pragma unroll
                for (int u = 0; u < 2; u++)
                    acc[t][u] = __builtin_amdgcn_mfma_f32_32x32x16_bf16(af[t], bfv[u], acc[t][u], 0, 0, 0);
        }
        __syncthreads();
    }

    // Epilogue: 32x32 C/D layout col = lane&31, row = (reg&3) + 8*(reg>>2) + 4*half.
    #pragma unroll
    for (int u = 0; u < 2; u++) {
        int n = (int)bn + wn * 64 + u * 32 + ml;
        float bj = bias[n];
#pragma unroll
        for (int t = 0; t < 2; t++) {
            int mb = (int)bm + wm * 64 + t * 32 + half * 4;
#pragma unroll
            for (int g = 0; g < 4; g++) {
#pragma unroll
                for (int d = 0; d < 4; d++) {
                    int row = mb + g * 8 + d;
                    C[(size_t)row * N_DIM + n] = acc[t][u][g * 4 + d] + bj;
                }
            }
        }
    }
}

extern "C" void kernel_launch(void* const* d_in, const int* in_sizes, int n_in,
                              void* d_out, int out_size, void* d_ws, size_t ws_size,
                              hipStream_t stream) {
    const float* x    = (const float*)d_in[0];   // [4,2048,4096]
    const float* w    = (const float*)d_in[1];   // [4096,4096]
    const float* bias = (const float*)d_in[2];   // [4096]
    float* out = (float*)d_out;

    uint16_t* xb   = (uint16_t*)d_ws;
    uint16_t* weff = (uint16_t*)((char*)d_ws + (size_t)M_DIM * K_DIM * 2);

    long long n8 = (long long)M_DIM * K_DIM / 8;
    cvt_x<<<dim3((unsigned)((n8 + 255) / 256)), dim3(256), 0, stream>>>(x, xb, n8);
    make_weff<<<dim3(N_DIM), dim3(256), 0, stream>>>(w, weff);
    gemm_bt<<<dim3(N_DIM / BN, M_DIM / BM), dim3(256), 0, stream>>>(xb, weff, bias, out);
}

// Round 3
// 510.366 us; speedup vs baseline: 1.0999x; 1.0372x over previous
//
#include <hip/hip_runtime.h>
#include <stdint.h>

// out[M,N] = x[M,K] @ w_eff[N,K]^T + bias[N]
#define M_DIM 8192
#define N_DIM 4096
#define K_DIM 4096

#define BM 128
#define BN 256
#define BK 64

typedef float v16f __attribute__((ext_vector_type(16)));
typedef __bf16 v8bf __attribute__((ext_vector_type(8)));

typedef __attribute__((address_space(3))) uint32_t lds_u32_t;
typedef const __attribute__((address_space(1))) uint32_t glb_u32_t;

__device__ inline uint16_t f2bf(float f) {
    union { float f; uint32_t u; } v; v.f = f;
    uint32_t r = v.u + 0x7fffu + ((v.u >> 16) & 1u);   // RNE
    return (uint16_t)(r >> 16);
}

// ---------------- kernel 1: x fp32 -> bf16 ----------------
__global__ __launch_bounds__(256) void cvt_x(const float* __restrict__ x,
                                             uint16_t* __restrict__ xb,
                                             long long n8) {
    long long i = (long long)blockIdx.x * 256 + threadIdx.x;
    if (i >= n8) return;
    const float4* x4 = (const float4*)x;
    float4 a = x4[2 * i];
    float4 b = x4[2 * i + 1];
    union { uint16_t h[8]; uint4 u; } o;
    o.h[0] = f2bf(a.x); o.h[1] = f2bf(a.y); o.h[2] = f2bf(a.z); o.h[3] = f2bf(a.w);
    o.h[4] = f2bf(b.x); o.h[5] = f2bf(b.y); o.h[6] = f2bf(b.z); o.h[7] = f2bf(b.w);
    ((uint4*)xb)[i] = o.u;
}

// ---------------- kernel 2: build w_eff (bf16, [N,K] = B^T layout) ----------------
__global__ __launch_bounds__(256) void make_weff(const float* __restrict__ w,
                                                 uint16_t* __restrict__ weff) {
    __shared__ double red[4];
    int row  = blockIdx.x;
    int tid  = threadIdx.x;
    int lane = tid & 63;
    int wid  = tid >> 6;

    const float* wr = w + (size_t)row * K_DIM;
    const float4* w4 = (const float4*)wr + tid * 4;
    float4 r0 = w4[0], r1 = w4[1], r2 = w4[2], r3 = w4[3];
    float v[16] = { r0.x, r0.y, r0.z, r0.w, r1.x, r1.y, r1.z, r1.w,
                    r2.x, r2.y, r2.z, r2.w, r3.x, r3.y, r3.z, r3.w };

    double s = 0.0;
#pragma unroll
    for (int j = 0; j < 16; j++) s += (double)v[j];
#pragma unroll
    for (int off = 32; off > 0; off >>= 1) s += __shfl_down(s, off);
    if (lane == 0) red[wid] = s;
    __syncthreads();
    double mu = (red[0] + red[1] + red[2] + red[3]) * (1.0 / 4096.0);
    __syncthreads();

    double sa = 0.0;
#pragma unroll
    for (int j = 0; j < 16; j++) sa += fabs((double)v[j] - mu);
#pragma unroll
    for (int off = 32; off > 0; off >>= 1) sa += __shfl_down(sa, off);
    if (lane == 0) red[wid] = sa;
    __syncthreads();
    double scale = (red[0] + red[1] + red[2] + red[3]) * (1.0 / 4096.0);

    float scf = (float)scale;
    union { uint16_t h[16]; uint4 u[2]; } o;
#pragma unroll
    for (int w2 = 0; w2 < 2; w2++) {
        int base = w2 * 8;
        int amax = 0;
        float mx = fabsf(v[base]);
#pragma unroll
        for (int j = 1; j < 8; j++) {
            float aj = fabsf(v[base + j]);
            if (aj > mx) { mx = aj; amax = j; }
        }
#pragma unroll
        for (int j = 0; j < 8; j++) {
            double wc = (double)v[base + j] - mu;
            float q = (wc > 0.0) ? scf : ((wc < 0.0) ? -scf : 0.0f);
            o.h[base + j] = f2bf((j == amax) ? v[base + j] : q);
        }
    }
    uint4* dst = (uint4*)(weff + (size_t)row * K_DIM + (size_t)tid * 16);
    dst[0] = o.u[0];
    dst[1] = o.u[1];
}

// ---------------- kernel 3: bf16 MFMA GEMM, 32x32x16, BK=64, 64x128 wave tile ----------------
// LDS-read-BW-bound fix: wave tile 64x128 (2x4 of 32x32) -> 0.75 ds_read per MFMA
// (was 1.0 at 64x64). LDS layout: rows of 8 chunks (16 B), chunk (r,c) at slot
// c^(r&7); swizzle baked into the GLOBAL fetch address (global_load_lds writes
// lane i at uniform_base + i*16).
__device__ inline void async_cp16(const uint16_t* g, uint16_t* lds_uniform) {
    __builtin_amdgcn_global_load_lds((glb_u32_t*)g, (lds_u32_t*)lds_uniform, 16, 0, 0);
}

__global__ __launch_bounds__(256, 2) void gemm_bt(const uint16_t* __restrict__ A,
                                                  const uint16_t* __restrict__ B,
                                                  const float* __restrict__ bias,
                                                  float* __restrict__ C) {
    __shared__ __attribute__((aligned(16))) uint16_t As[BM * BK];   // 16 KB
    __shared__ __attribute__((aligned(16))) uint16_t Bs[BN * BK];   // 32 KB

    int tid  = threadIdx.x;
    int lane = tid & 63;
    int wid  = tid >> 6;          // 4 waves, 2(m) x 2(n); wave tile 64x128
    int wm   = wid >> 1;
    int wn   = wid & 1;
    int half = lane >> 5;
    int ml   = lane & 31;

    long long bm = (long long)blockIdx.y * BM;
    long long bn = (long long)blockIdx.x * BN;

    v16f acc[2][4];
#pragma unroll
    for (int t = 0; t < 2; t++)
#pragma unroll
        for (int u = 0; u < 4; u++) acc[t][u] = (v16f)(0.0f);

    const uint16_t* Ab = A + (size_t)bm * K_DIM;
    const uint16_t* Bb = B + (size_t)bn * K_DIM;

    // Staging: chunk block ib covers 8 rows x 8 chunk-cols (64 x 16 B = 1 KB).
    // Lane: row = ib*8 + (lane>>3), stored col = lane&7, global col = (lane&7)^(lane>>3).
    int lrow = lane >> 3;
    int cg   = (lane & 7) ^ lrow;

    for (int k0 = 0; k0 < K_DIM; k0 += BK) {
#pragma unroll
        for (int q = 0; q < 4; q++) {            // As: 16 blocks of 1 KB
            int ib = wid * 4 + q;
            int r  = ib * 8 + lrow;
            async_cp16(Ab + (size_t)r * K_DIM + k0 + cg * 8, As + ib * 512);
        }
#pragma unroll
        for (int q = 0; q < 8; q++) {            // Bs: 32 blocks of 1 KB
            int ib = wid * 8 + q;
            int r  = ib * 8 + lrow;
            async_cp16(Bb + (size_t)r * K_DIM + k0 + cg * 8, Bs + ib * 512);
        }
        __syncthreads();

#pragma unroll
        for (int s = 0; s < 4; s++) {            // 4 k-steps of 16
            int cc = s * 2 + half;
            v8bf af[2], bfv[4];
#pragma unroll
            for (int t = 0; t < 2; t++) {
                int r = wm * 64 + t * 32 + ml;
                af[t] = *(const v8bf*)&As[r * BK + ((cc ^ (r & 7)) * 8)];
            }
#pragma unroll
            for (int u = 0; u < 4; u++) {
                int r = wn * 128 + u * 32 + ml;
                bfv[u] = *(const v8bf*)&Bs[r * BK + ((cc ^ (r & 7)) * 8)];
            }
#pragma unroll
            for (int t = 0; t < 2; t++)
#pragma unroll
                for (int u = 0; u < 4; u++)
                    acc[t][u] = __builtin_amdgcn_mfma_f32_32x32x16_bf16(af[t], bfv[u], acc[t][u], 0, 0, 0);
        }
        __syncthreads();
    }

    // Epilogue: 32x32 C/D layout col = lane&31, row = (reg&3) + 8*(reg>>2) + 4*half.
#pragma unroll
    for (int u = 0; u < 4; u++) {
        int n = (int)bn + wn * 128 + u * 32 + ml;
        float bj = bias[n];
#pragma unroll
        for (int t = 0; t < 2; t++) {
            int mb = (int)bm + wm * 64 + t * 32 + half * 4;
#pragma unroll
            for (int g = 0; g < 4; g++) {
#pragma unroll
                for (int d = 0; d < 4; d++) {
                    int row = mb + g * 8 + d;
                    C[(size_t)row * N_DIM + n] = acc[t][u][g * 4 + d] + bj;
                }
            }
        }
    }
}

extern "C" void kernel_launch(void* const* d_in, const int* in_sizes, int n_in,
                              void* d_out, int out_size, void* d_ws, size_t ws_size,
                              hipStream_t stream) {
    const float* x    = (const float*)d_in[0];   // [4,2048,4096]
    const float* w    = (const float*)d_in[1];   // [4096,4096]
    const float* bias = (const float*)d_in[2];   // [4096]
    float* out = (float*)d_out;

    uint16_t* xb   = (uint16_t*)d_ws;
    uint16_t* weff = (uint16_t*)((char*)d_ws + (size_t)M_DIM * K_DIM * 2);

    long long n8 = (long long)M_DIM * K_DIM / 8;
    cvt_x<<<dim3((unsigned)((n8 + 255) / 256)), dim3(256), 0, stream>>>(x, xb, n8);
    make_weff<<<dim3(N_DIM), dim3(256), 0, stream>>>(w, weff);
    gemm_bt<<<dim3(N_DIM / BN, M_DIM / BM), dim3(256), 0, stream>>>(xb, weff, bias, out);
}